// Round 1
// baseline (542.419 us; speedup 1.0000x reference)
//
#include <hip/hip_runtime.h>
#include <hip/hip_bf16.h>
#include <cstdint>
#include <cstddef>

typedef __attribute__((ext_vector_type(8))) __bf16 bf16x8;
typedef __attribute__((ext_vector_type(4))) float f32x4;

#define MFMA16(a, b, c) __builtin_amdgcn_mfma_f32_16x16x32_bf16((a), (b), (c), 0, 0, 0)

__device__ __forceinline__ bf16x8 cvt8(const float* __restrict__ p) {
    const float4 a = *(const float4*)p;
    const float4 b = *(const float4*)(p + 4);
    bf16x8 r;
    r[0] = (__bf16)a.x; r[1] = (__bf16)a.y; r[2] = (__bf16)a.z; r[3] = (__bf16)a.w;
    r[4] = (__bf16)b.x; r[5] = (__bf16)b.y; r[6] = (__bf16)b.z; r[7] = (__bf16)b.w;
    return r;
}

// ---------------------------------------------------------------------------
// K0a: x [2][4096][256] fp32  ->  xT [2][256][4096] bf16   (tile transpose)
// grid = 2 * 64 * 4 = 512 blocks, 256 threads
// ---------------------------------------------------------------------------
__global__ __launch_bounds__(256) void k0a(const float* __restrict__ x,
                                           __bf16* __restrict__ xT) {
    __shared__ float tile[64][65];
    const int bid = blockIdx.x;
    const int b = bid >> 8;
    const int rem = bid & 255;
    const int tt = rem >> 2, dd = rem & 3;
    const int t0 = tt * 64, d0 = dd * 64;
    #pragma unroll
    for (int j = 0; j < 16; ++j) {
        int idx = j * 256 + threadIdx.x;
        int t = idx >> 6, d = idx & 63;
        tile[t][d] = x[((size_t)(b * 4096 + t0 + t)) * 256 + d0 + d];
    }
    __syncthreads();
    #pragma unroll
    for (int j = 0; j < 16; ++j) {
        int idx = j * 256 + threadIdx.x;
        int d = idx >> 6, t = idx & 63;
        xT[((size_t)(b * 256 + d0 + d)) * 4096 + t0 + t] = (__bf16)tile[t][d];
    }
}

// ---------------------------------------------------------------------------
// K0b: VO [8][256][256] fp32 -> VOT [256][2048] bf16, VOT[e][h*256+d] = VO[h][d][e]
// grid = 8 * 16 = 128 blocks, 256 threads
// ---------------------------------------------------------------------------
__global__ __launch_bounds__(256) void k0b(const float* __restrict__ VO,
                                           __bf16* __restrict__ vot) {
    __shared__ float tile[64][65];
    const int bid = blockIdx.x;
    const int h = bid >> 4;
    const int rem = bid & 15;
    const int dt = rem >> 2, et = rem & 3;
    const int d0 = dt * 64, e0 = et * 64;
    #pragma unroll
    for (int j = 0; j < 16; ++j) {
        int idx = j * 256 + threadIdx.x;
        int d = idx >> 6, e = idx & 63;
        tile[d][e] = VO[((size_t)(h * 256 + d0 + d)) * 256 + e0 + e];
    }
    __syncthreads();
    #pragma unroll
    for (int j = 0; j < 16; ++j) {
        int idx = j * 256 + threadIdx.x;
        int e = idx >> 6, d = idx & 63;
        vot[((size_t)(e0 + e)) * 2048 + h * 256 + d0 + d] = (__bf16)tile[d][e];
    }
}

// ---------------------------------------------------------------------------
// proj: q[b,h,t,r] = sum_d x[b,t,d] * Q[h,r,d]  (and same for K)
// Output layout: [B][H][T][32] bf16.  One wave = 16 t-rows x 32 r for one (h,s).
// grid = 2048 blocks x 256 threads (8192 wave-tasks)
// ---------------------------------------------------------------------------
__global__ __launch_bounds__(256) void proj_kernel(const float* __restrict__ x,
                                                   const float* __restrict__ Qw,
                                                   const float* __restrict__ Kw,
                                                   __bf16* __restrict__ qo,
                                                   __bf16* __restrict__ ko) {
    const int task = blockIdx.x * 4 + (threadIdx.x >> 6);
    const int l = threadIdx.x & 63;
    const int g = l >> 4, c = l & 15;
    const int tt = task >> 4;
    const int rem = task & 15;
    const int h = rem >> 1, s = rem & 1;
    const int tg = tt * 16;  // global row in [0, 8192)
    const float* W = s ? Kw : Qw;
    __bf16* outp = s ? ko : qo;

    f32x4 acc0 = {0.f, 0.f, 0.f, 0.f}, acc1 = {0.f, 0.f, 0.f, 0.f};
    #pragma unroll
    for (int kk = 0; kk < 8; ++kk) {
        bf16x8 a  = cvt8(&x[((size_t)(tg + c)) * 256 + kk * 32 + g * 8]);
        bf16x8 b0 = cvt8(&W[((size_t)(h * 32 + c)) * 256 + kk * 32 + g * 8]);
        bf16x8 b1 = cvt8(&W[((size_t)(h * 32 + 16 + c)) * 256 + kk * 32 + g * 8]);
        acc0 = MFMA16(a, b0, acc0);
        acc1 = MFMA16(a, b1, acc1);
    }
    const int b = tg >> 12, t = tg & 4095;
    const size_t obase = (size_t)(b * 8 + h) * 4096 + t;
    #pragma unroll
    for (int i = 0; i < 4; ++i) {
        outp[(obase + 4 * g + i) * 32 + c]      = (__bf16)acc0[i];
        outp[(obase + 4 * g + i) * 32 + 16 + c] = (__bf16)acc1[i];
    }
}

// ---------------------------------------------------------------------------
// attn: flash attention. block = one (b,h) x 64 t-rows; 4 waves x 16 rows.
// u-tiles of 64.  S-tile = single 16x16x32 MFMA (R=32).  ctx out bf16
// [B][T][H][256] (i.e. [B*T][2048] for the final GEMM).
// grid = 16 * 64 = 1024 blocks, 256 threads
// ---------------------------------------------------------------------------
__global__ __launch_bounds__(256) void attn_kernel(const __bf16* __restrict__ qg,
                                                   const __bf16* __restrict__ kg,
                                                   const __bf16* __restrict__ xTg,
                                                   __bf16* __restrict__ ctx) {
    // kbuf [64][40] bf16 (80B rows)   = 5120 B
    // xbuf [256][72] bf16 (144B rows) = 36864 B
    // pbuf 4 waves x [16][72] bf16    = 9216 B
    __shared__ __align__(16) unsigned char lds[5120 + 36864 + 4 * 2304];
    unsigned char* kbuf = lds;
    unsigned char* xbuf = lds + 5120;
    unsigned char* pbuf = lds + 5120 + 36864;

    const int bid = blockIdx.x;
    const int bh = bid >> 6;
    const int tt = bid & 63;
    const int b = bh >> 3, h = bh & 7;
    const int t0 = tt * 64;
    const int tid = threadIdx.x;
    const int w = tid >> 6;
    const int l = tid & 63;
    const int g = l >> 4, c = l & 15;

    // q A-fragment: 16 rows x 32 (K=32 = full R)
    const bf16x8 qa = *(const bf16x8*)(qg + ((size_t)bh * 4096 + t0 + w * 16 + c) * 32 + g * 8);

    f32x4 acc[16];
    #pragma unroll
    for (int j = 0; j < 16; ++j) acc[j] = (f32x4){0.f, 0.f, 0.f, 0.f};
    float m2[4]   = {-3e38f, -3e38f, -3e38f, -3e38f};
    float lsum[4] = {0.f, 0.f, 0.f, 0.f};
    const float cl = 1.4426950408889634f / 16.0f;  // log2(e)/sqrt(D)

    const size_t kbase = (size_t)bh * 4096 * 32;
    const size_t xbase = (size_t)b * 256 * 4096;
    unsigned char* mypb = pbuf + w * 2304;

    for (int ut = 0; ut < 64; ++ut) {
        const int u0 = ut * 64;
        __syncthreads();  // protect previous tile's LDS reads
        {   // stage k tile [64][32] -> kbuf rows of 80 B
            int r = tid >> 2, cc = tid & 3;
            uint4 v = *(const uint4*)(kg + kbase + (size_t)(u0 + r) * 32 + cc * 8);
            *(uint4*)(kbuf + r * 80 + cc * 16) = v;
        }
        #pragma unroll
        for (int j = 0; j < 8; ++j) {  // stage xT tile [256 d][64 u] -> 144 B rows
            int ch = j * 256 + tid;
            int d = ch >> 3, cc = ch & 7;
            uint4 v = *(const uint4*)(xTg + xbase + (size_t)d * 4096 + u0 + cc * 8);
            *(uint4*)(xbuf + d * 144 + cc * 16) = v;
        }
        __syncthreads();

        // ---- S = q * k^T (pre-scaled into log2 domain) ----
        float pv[4][4];
        #pragma unroll
        for (int ub = 0; ub < 4; ++ub) {
            bf16x8 kb = *(const bf16x8*)(kbuf + (ub * 16 + c) * 80 + g * 16);
            f32x4 s = MFMA16(qa, kb, ((f32x4){0.f, 0.f, 0.f, 0.f}));
            #pragma unroll
            for (int i = 0; i < 4; ++i) pv[ub][i] = s[i] * cl;
        }
        // ---- online softmax (rows = 4g+i, cols spread over 16 lanes x 4 ub) ----
        float mx[4];
        #pragma unroll
        for (int i = 0; i < 4; ++i)
            mx[i] = fmaxf(fmaxf(pv[0][i], pv[1][i]), fmaxf(pv[2][i], pv[3][i]));
        #pragma unroll
        for (int d = 1; d < 16; d <<= 1) {
            #pragma unroll
            for (int i = 0; i < 4; ++i) mx[i] = fmaxf(mx[i], __shfl_xor(mx[i], d));
        }
        float scale[4], rs[4];
        #pragma unroll
        for (int i = 0; i < 4; ++i) {
            float mn = fmaxf(m2[i], mx[i]);
            scale[i] = __builtin_amdgcn_exp2f(m2[i] - mn);
            m2[i] = mn;
            rs[i] = 0.f;
        }
        #pragma unroll
        for (int ub = 0; ub < 4; ++ub) {
            #pragma unroll
            for (int i = 0; i < 4; ++i) {
                float p = __builtin_amdgcn_exp2f(pv[ub][i] - m2[i]);
                pv[ub][i] = p;
                rs[i] += p;
            }
        }
        #pragma unroll
        for (int d = 1; d < 16; d <<= 1) {
            #pragma unroll
            for (int i = 0; i < 4; ++i) rs[i] += __shfl_xor(rs[i], d);
        }
        #pragma unroll
        for (int i = 0; i < 4; ++i) lsum[i] = lsum[i] * scale[i] + rs[i];
        #pragma unroll
        for (int j = 0; j < 16; ++j) {
            #pragma unroll
            for (int i = 0; i < 4; ++i) acc[j][i] *= scale[i];
        }
        // ---- redistribute P (C-layout -> A-frag layout) via per-wave LDS ----
        #pragma unroll
        for (int ub = 0; ub < 4; ++ub) {
            #pragma unroll
            for (int i = 0; i < 4; ++i)
                *(__bf16*)(mypb + (4 * g + i) * 144 + (ub * 16 + c) * 2) = (__bf16)pv[ub][i];
        }
        bf16x8 pa0 = *(const bf16x8*)(mypb + c * 144 + 0 * 64 + g * 16);
        bf16x8 pa1 = *(const bf16x8*)(mypb + c * 144 + 1 * 64 + g * 16);
        // ---- PV: acc[j] += P[16x64] * x[64 x d-tile j] ----
        #pragma unroll
        for (int j = 0; j < 16; ++j) {
            bf16x8 xb0 = *(const bf16x8*)(xbuf + (j * 16 + c) * 144 + 0 * 64 + g * 16);
            acc[j] = MFMA16(pa0, xb0, acc[j]);
            bf16x8 xb1 = *(const bf16x8*)(xbuf + (j * 16 + c) * 144 + 1 * 64 + g * 16);
            acc[j] = MFMA16(pa1, xb1, acc[j]);
        }
    }
    // ---- epilogue: ctx[b][t][h][d] = acc / lsum ----
    float inv[4];
    #pragma unroll
    for (int i = 0; i < 4; ++i) inv[i] = 1.0f / lsum[i];
    #pragma unroll
    for (int j = 0; j < 16; ++j) {
        #pragma unroll
        for (int i = 0; i < 4; ++i) {
            int t = t0 + w * 16 + 4 * g + i;
            ctx[((size_t)(b * 4096 + t) * 8 + h) * 256 + j * 16 + c] = (__bf16)(acc[j][i] * inv[i]);
        }
    }
}

// ---------------------------------------------------------------------------
// gemm_out: out[bt][e] = sum_k ctx[bt][k] * VOT[e][k],  M=8192 K=2048 N=256
// grid = 2048 blocks x 256 threads (8192 wave-tiles of 16x16)
// ---------------------------------------------------------------------------
__global__ __launch_bounds__(256) void gemm_out(const __bf16* __restrict__ ctx,
                                                const __bf16* __restrict__ vot,
                                                float* __restrict__ out) {
    const int task = blockIdx.x * 4 + (threadIdx.x >> 6);
    const int l = threadIdx.x & 63;
    const int g = l >> 4, c = l & 15;
    const int mt = task >> 4, nt = task & 15;
    const size_t arow = (size_t)(mt * 16 + c) * 2048;
    const size_t brow = (size_t)(nt * 16 + c) * 2048;
    f32x4 acc = {0.f, 0.f, 0.f, 0.f};
    #pragma unroll 8
    for (int kk = 0; kk < 64; ++kk) {
        bf16x8 a = *(const bf16x8*)(ctx + arow + kk * 32 + g * 8);
        bf16x8 b = *(const bf16x8*)(vot + brow + kk * 32 + g * 8);
        acc = MFMA16(a, b, acc);
    }
    #pragma unroll
    for (int i = 0; i < 4; ++i)
        out[(size_t)(mt * 16 + 4 * g + i) * 256 + nt * 16 + c] = acc[i];
}

// ---------------------------------------------------------------------------
extern "C" void kernel_launch(void* const* d_in, const int* in_sizes, int n_in,
                              void* d_out, int out_size, void* d_ws, size_t ws_size,
                              hipStream_t stream) {
    const float* x  = (const float*)d_in[0];  // [2][4096][256]
    const float* Qw = (const float*)d_in[1];  // [8][32][256]
    const float* Kw = (const float*)d_in[2];  // [8][32][256]
    const float* VO = (const float*)d_in[3];  // [8][256][256]
    float* out = (float*)d_out;               // [2][4096][256]

    char* ws = (char*)d_ws;
    __bf16* xT  = (__bf16*)(ws);                          // 4 MB  [2][256][4096]
    __bf16* qb  = (__bf16*)(ws + ((size_t)4 << 20));      // 4 MB  [2][8][4096][32]
    __bf16* kb  = (__bf16*)(ws + ((size_t)8 << 20));      // 4 MB
    __bf16* vot = (__bf16*)(ws + ((size_t)12 << 20));     // 1 MB  [256][2048]
    __bf16* ctx = (__bf16*)(ws + ((size_t)13 << 20));     // 32 MB [2][4096][8][256]

    k0a<<<512, 256, 0, stream>>>(x, xT);
    k0b<<<128, 256, 0, stream>>>(VO, vot);
    proj_kernel<<<2048, 256, 0, stream>>>(x, Qw, Kw, qb, kb);
    attn_kernel<<<1024, 256, 0, stream>>>(qb, kb, xT, ctx);
    gemm_out<<<2048, 256, 0, stream>>>(ctx, vot, out);
}

// Round 2
// 435.337 us; speedup vs baseline: 1.2460x; 1.2460x over previous
//
#include <hip/hip_runtime.h>
#include <hip/hip_bf16.h>
#include <cstdint>
#include <cstddef>

typedef __attribute__((ext_vector_type(8))) __bf16 bf16x8;
typedef __attribute__((ext_vector_type(4))) float f32x4;
typedef __attribute__((ext_vector_type(16))) float f32x16;

#define MFMA16(a, b, c) __builtin_amdgcn_mfma_f32_16x16x32_bf16((a), (b), (c), 0, 0, 0)
#define MFMA32(a, b, c) __builtin_amdgcn_mfma_f32_32x32x16_bf16((a), (b), (c), 0, 0, 0)

__device__ __forceinline__ bf16x8 cvt8(const float* __restrict__ p) {
    const float4 a = *(const float4*)p;
    const float4 b = *(const float4*)(p + 4);
    bf16x8 r;
    r[0] = (__bf16)a.x; r[1] = (__bf16)a.y; r[2] = (__bf16)a.z; r[3] = (__bf16)a.w;
    r[4] = (__bf16)b.x; r[5] = (__bf16)b.y; r[6] = (__bf16)b.z; r[7] = (__bf16)b.w;
    return r;
}

// ---------------------------------------------------------------------------
// K0a: x [2][4096][256] fp32  ->  xT [2][256][4096] bf16   (tile transpose)
// ---------------------------------------------------------------------------
__global__ __launch_bounds__(256) void k0a(const float* __restrict__ x,
                                           __bf16* __restrict__ xT) {
    __shared__ float tile[64][65];
    const int bid = blockIdx.x;
    const int b = bid >> 8;
    const int rem = bid & 255;
    const int tt = rem >> 2, dd = rem & 3;
    const int t0 = tt * 64, d0 = dd * 64;
    #pragma unroll
    for (int j = 0; j < 16; ++j) {
        int idx = j * 256 + threadIdx.x;
        int t = idx >> 6, d = idx & 63;
        tile[t][d] = x[((size_t)(b * 4096 + t0 + t)) * 256 + d0 + d];
    }
    __syncthreads();
    #pragma unroll
    for (int j = 0; j < 16; ++j) {
        int idx = j * 256 + threadIdx.x;
        int d = idx >> 6, t = idx & 63;
        xT[((size_t)(b * 256 + d0 + d)) * 4096 + t0 + t] = (__bf16)tile[t][d];
    }
}

// ---------------------------------------------------------------------------
// K0b: VO [8][256][256] fp32 -> VOT [256][2048] bf16, VOT[e][h*256+d] = VO[h][d][e]
// ---------------------------------------------------------------------------
__global__ __launch_bounds__(256) void k0b(const float* __restrict__ VO,
                                           __bf16* __restrict__ vot) {
    __shared__ float tile[64][65];
    const int bid = blockIdx.x;
    const int h = bid >> 4;
    const int rem = bid & 15;
    const int dt = rem >> 2, et = rem & 3;
    const int d0 = dt * 64, e0 = et * 64;
    #pragma unroll
    for (int j = 0; j < 16; ++j) {
        int idx = j * 256 + threadIdx.x;
        int d = idx >> 6, e = idx & 63;
        tile[d][e] = VO[((size_t)(h * 256 + d0 + d)) * 256 + e0 + e];
    }
    __syncthreads();
    #pragma unroll
    for (int j = 0; j < 16; ++j) {
        int idx = j * 256 + threadIdx.x;
        int e = idx >> 6, d = idx & 63;
        vot[((size_t)(e0 + e)) * 2048 + h * 256 + d0 + d] = (__bf16)tile[d][e];
    }
}

// ---------------------------------------------------------------------------
// proj: q[b,h,t,r] = sum_d x[b,t,d] * Q[h,r,d]  (and same for K)
// ---------------------------------------------------------------------------
__global__ __launch_bounds__(256) void proj_kernel(const float* __restrict__ x,
                                                   const float* __restrict__ Qw,
                                                   const float* __restrict__ Kw,
                                                   __bf16* __restrict__ qo,
                                                   __bf16* __restrict__ ko) {
    const int task = blockIdx.x * 4 + (threadIdx.x >> 6);
    const int l = threadIdx.x & 63;
    const int g = l >> 4, c = l & 15;
    const int tt = task >> 4;
    const int rem = task & 15;
    const int h = rem >> 1, s = rem & 1;
    const int tg = tt * 16;
    const float* W = s ? Kw : Qw;
    __bf16* outp = s ? ko : qo;

    f32x4 acc0 = {0.f, 0.f, 0.f, 0.f}, acc1 = {0.f, 0.f, 0.f, 0.f};
    #pragma unroll
    for (int kk = 0; kk < 8; ++kk) {
        bf16x8 a  = cvt8(&x[((size_t)(tg + c)) * 256 + kk * 32 + g * 8]);
        bf16x8 b0 = cvt8(&W[((size_t)(h * 32 + c)) * 256 + kk * 32 + g * 8]);
        bf16x8 b1 = cvt8(&W[((size_t)(h * 32 + 16 + c)) * 256 + kk * 32 + g * 8]);
        acc0 = MFMA16(a, b0, acc0);
        acc1 = MFMA16(a, b1, acc1);
    }
    const int b = tg >> 12, t = tg & 4095;
    const size_t obase = (size_t)(b * 8 + h) * 4096 + t;
    #pragma unroll
    for (int i = 0; i < 4; ++i) {
        outp[(obase + 4 * g + i) * 32 + c]      = (__bf16)acc0[i];
        outp[(obase + 4 * g + i) * 32 + 16 + c] = (__bf16)acc1[i];
    }
}

// ---------------------------------------------------------------------------
// attn v2: block = one (b,h) x 64 t-rows, 4 waves.
//   Phase A: each wave computes scores for its 16 t-rows (k-frags straight
//            from L2), softmax, writes P (bf16, swizzled) + scales to LDS.
//   Phase B: each wave owns a 64-wide d-slice of ALL 64 t-rows; PV uses
//            32x32x16 MFMA on shared P and the swizzled x-tile.
//   x-tile staged via global_load_lds (pre-swizzled source), double-buffered.
// grid = 1024 blocks x 256 threads
// ---------------------------------------------------------------------------
__device__ __forceinline__ void stage_x(const __bf16* __restrict__ xTg_b,
                                        unsigned char* xhalf, int u0, int tid) {
    #pragma unroll
    for (int j = 0; j < 8; ++j) {
        int ch = j * 256 + tid;
        int d = ch >> 3;
        int slog = (ch & 7) ^ (d & 7);
        const __bf16* src = xTg_b + (size_t)d * 4096 + u0 + slog * 8;
        unsigned char* dst = xhalf + (size_t)(j * 256 + (tid & 192)) * 16;  // wave-uniform
        __builtin_amdgcn_global_load_lds(
            (const __attribute__((address_space(1))) unsigned int*)src,
            (__attribute__((address_space(3))) unsigned int*)dst, 16, 0, 0);
    }
}

__device__ __forceinline__ void load_k(bf16x8 kreg[4], const __bf16* __restrict__ kg_bh,
                                       int u0, int c, int g) {
    #pragma unroll
    for (int ub = 0; ub < 4; ++ub)
        kreg[ub] = *(const bf16x8*)(kg_bh + (size_t)(u0 + ub * 16 + c) * 32 + g * 8);
}

__global__ __launch_bounds__(256, 2) void attn_kernel(const __bf16* __restrict__ qg,
                                                      const __bf16* __restrict__ kg,
                                                      const __bf16* __restrict__ xTg,
                                                      __bf16* __restrict__ ctx) {
    __shared__ __align__(16) unsigned char lds[65536 + 8192 + 256];
    unsigned char* xbuf0 = lds;
    unsigned char* xbuf1 = lds + 32768;
    unsigned char* pbuf  = lds + 65536;
    float* scale_lds = (float*)(lds + 65536 + 8192);

    const int bid = blockIdx.x;
    const int bh = bid >> 6;
    const int tt = bid & 63;
    const int b = bh >> 3, h = bh & 7;
    const int t0 = tt * 64;
    const int tid = threadIdx.x;
    const int w = tid >> 6;
    const int l = tid & 63;
    const int g = l >> 4, c = l & 15;
    const int l31 = l & 31, hi = l >> 5;

    const __bf16* xTg_b = xTg + (size_t)b * 256 * 4096;
    const __bf16* kg_bh = kg + (size_t)bh * 4096 * 32;

    const bf16x8 qa = *(const bf16x8*)(qg + ((size_t)bh * 4096 + t0 + w * 16 + c) * 32 + g * 8);

    f32x16 acc[2][2];
    #pragma unroll
    for (int m = 0; m < 2; ++m)
        #pragma unroll
        for (int n = 0; n < 2; ++n)
            #pragma unroll
            for (int r = 0; r < 16; ++r) acc[m][n][r] = 0.f;
    float m2[4]   = {-3e38f, -3e38f, -3e38f, -3e38f};
    float lsum[4] = {0.f, 0.f, 0.f, 0.f};
    const float cl = 1.4426950408889634f / 16.0f;  // log2(e)/sqrt(D)

    stage_x(xTg_b, xbuf0, 0, tid);
    bf16x8 kreg[4];
    load_k(kreg, kg_bh, 0, c, g);
    __syncthreads();

    for (int ut = 0; ut < 64; ++ut) {
        unsigned char* xcur = (ut & 1) ? xbuf1 : xbuf0;
        unsigned char* xnxt = (ut & 1) ? xbuf0 : xbuf1;

        // ---- Phase A: scores + online softmax for this wave's 16 t-rows ----
        float pv[4][4];
        #pragma unroll
        for (int ub = 0; ub < 4; ++ub) {
            f32x4 s = MFMA16(qa, kreg[ub], ((f32x4){0.f, 0.f, 0.f, 0.f}));
            #pragma unroll
            for (int i = 0; i < 4; ++i) pv[ub][i] = s[i] * cl;
        }
        if (ut < 63) load_k(kreg, kg_bh, (ut + 1) * 64, c, g);  // prefetch next k

        float mx[4];
        #pragma unroll
        for (int i = 0; i < 4; ++i)
            mx[i] = fmaxf(fmaxf(pv[0][i], pv[1][i]), fmaxf(pv[2][i], pv[3][i]));
        #pragma unroll
        for (int dd = 1; dd < 16; dd <<= 1) {
            #pragma unroll
            for (int i = 0; i < 4; ++i) mx[i] = fmaxf(mx[i], __shfl_xor(mx[i], dd));
        }
        float scale[4], rs[4];
        #pragma unroll
        for (int i = 0; i < 4; ++i) {
            float mn = fmaxf(m2[i], mx[i]);
            scale[i] = __builtin_amdgcn_exp2f(m2[i] - mn);
            m2[i] = mn;
            rs[i] = 0.f;
        }
        #pragma unroll
        for (int ub = 0; ub < 4; ++ub) {
            #pragma unroll
            for (int i = 0; i < 4; ++i) {
                float p = __builtin_amdgcn_exp2f(pv[ub][i] - m2[i]);
                pv[ub][i] = p;
                rs[i] += p;
            }
        }
        #pragma unroll
        for (int dd = 1; dd < 16; dd <<= 1) {
            #pragma unroll
            for (int i = 0; i < 4; ++i) rs[i] += __shfl_xor(rs[i], dd);
        }
        #pragma unroll
        for (int i = 0; i < 4; ++i) lsum[i] = lsum[i] * scale[i] + rs[i];

        // write P (bf16, XOR-swizzled rows of 128 B) + per-row scales
        #pragma unroll
        for (int ub = 0; ub < 4; ++ub) {
            #pragma unroll
            for (int i = 0; i < 4; ++i) {
                int row = w * 16 + 4 * g + i;
                int colb = (ub * 16 + c) * 2;
                *(__bf16*)(pbuf + row * 128 + (colb ^ ((row & 7) << 4))) = (__bf16)pv[ub][i];
            }
        }
        if (c < 4) scale_lds[w * 16 + 4 * g + c] = scale[c];
        __syncthreads();  // barrier1: P + scales visible

        if (ut < 63) stage_x(xTg_b, xnxt, (ut + 1) * 64, tid);  // overlap with PV

        // ---- Phase B: rescale + PV over this wave's d-slice ----
        f32x4 sc[2][4];
        bool allone = true;
        #pragma unroll
        for (int m = 0; m < 2; ++m) {
            #pragma unroll
            for (int q = 0; q < 4; ++q) {
                sc[m][q] = *(const f32x4*)&scale_lds[m * 32 + q * 8 + hi * 4];
                allone = allone & (sc[m][q][0] == 1.f) & (sc[m][q][1] == 1.f) &
                         (sc[m][q][2] == 1.f) & (sc[m][q][3] == 1.f);
            }
        }
        if (!__all(allone)) {
            #pragma unroll
            for (int m = 0; m < 2; ++m)
                #pragma unroll
                for (int n = 0; n < 2; ++n)
                    #pragma unroll
                    for (int r = 0; r < 16; ++r)
                        acc[m][n][r] *= sc[m][r >> 2][r & 3];
        }
        #pragma unroll
        for (int kt = 0; kt < 4; ++kt) {
            const int ub_byte = kt * 32 + hi * 16;
            bf16x8 pa[2], xb[2];
            #pragma unroll
            for (int m = 0; m < 2; ++m) {
                int row = m * 32 + l31;
                pa[m] = *(const bf16x8*)(pbuf + row * 128 + (ub_byte ^ ((row & 7) << 4)));
            }
            #pragma unroll
            for (int n = 0; n < 2; ++n) {
                int row = w * 64 + n * 32 + l31;
                xb[n] = *(const bf16x8*)(xcur + row * 128 + (ub_byte ^ ((row & 7) << 4)));
            }
            #pragma unroll
            for (int m = 0; m < 2; ++m)
                #pragma unroll
                for (int n = 0; n < 2; ++n)
                    acc[m][n] = MFMA32(pa[m], xb[n], acc[m][n]);
        }
        __syncthreads();  // barrier2: PV reads done; next-x stage drained
    }

    // ---- epilogue: share 1/lsum, normalize, store ctx[b][t][h][d] ----
    if (c < 4) scale_lds[w * 16 + 4 * g + c] = 1.0f / lsum[c];
    __syncthreads();
    f32x4 iv[2][4];
    #pragma unroll
    for (int m = 0; m < 2; ++m)
        #pragma unroll
        for (int q = 0; q < 4; ++q)
            iv[m][q] = *(const f32x4*)&scale_lds[m * 32 + q * 8 + hi * 4];
    #pragma unroll
    for (int m = 0; m < 2; ++m) {
        #pragma unroll
        for (int n = 0; n < 2; ++n) {
            #pragma unroll
            for (int r = 0; r < 16; ++r) {
                int t = t0 + m * 32 + (r & 3) + 8 * (r >> 2) + 4 * hi;
                int d = w * 64 + n * 32 + l31;
                ctx[((size_t)(b * 4096 + t) * 8 + h) * 256 + d] =
                    (__bf16)(acc[m][n][r] * iv[m][r >> 2][r & 3]);
            }
        }
    }
}

// ---------------------------------------------------------------------------
// gemm_out: out[bt][e] = sum_k ctx[bt][k] * VOT[e][k],  M=8192 K=2048 N=256
// 32x32 wave tiles: 2048 wave-tasks, grid = 512 blocks x 256 threads
// ---------------------------------------------------------------------------
__global__ __launch_bounds__(256) void gemm_out(const __bf16* __restrict__ ctx,
                                                const __bf16* __restrict__ vot,
                                                float* __restrict__ out) {
    const int task = blockIdx.x * 4 + (threadIdx.x >> 6);
    const int l = threadIdx.x & 63;
    const int l31 = l & 31, hi = l >> 5;
    const int mt = task >> 3, nt = task & 7;  // 256 m-tiles x 8 n-tiles
    const size_t arow = (size_t)(mt * 32 + l31) * 2048;
    const size_t brow = (size_t)(nt * 32 + l31) * 2048;
    f32x16 acc;
    #pragma unroll
    for (int r = 0; r < 16; ++r) acc[r] = 0.f;
    #pragma unroll 4
    for (int kk = 0; kk < 128; ++kk) {
        bf16x8 a = *(const bf16x8*)(ctx + arow + kk * 16 + hi * 8);
        bf16x8 b = *(const bf16x8*)(vot + brow + kk * 16 + hi * 8);
        acc = MFMA32(a, b, acc);
    }
    #pragma unroll
    for (int r = 0; r < 16; ++r) {
        int row = mt * 32 + (r & 3) + 8 * (r >> 2) + 4 * hi;
        out[(size_t)row * 256 + nt * 32 + l31] = acc[r];
    }
}

// ---------------------------------------------------------------------------
extern "C" void kernel_launch(void* const* d_in, const int* in_sizes, int n_in,
                              void* d_out, int out_size, void* d_ws, size_t ws_size,
                              hipStream_t stream) {
    const float* x  = (const float*)d_in[0];  // [2][4096][256]
    const float* Qw = (const float*)d_in[1];  // [8][32][256]
    const float* Kw = (const float*)d_in[2];  // [8][32][256]
    const float* VO = (const float*)d_in[3];  // [8][256][256]
    float* out = (float*)d_out;               // [2][4096][256]

    char* ws = (char*)d_ws;
    __bf16* xT  = (__bf16*)(ws);                          // 4 MB  [2][256][4096]
    __bf16* qb  = (__bf16*)(ws + ((size_t)4 << 20));      // 4 MB  [2][8][4096][32]
    __bf16* kb  = (__bf16*)(ws + ((size_t)8 << 20));      // 4 MB
    __bf16* vot = (__bf16*)(ws + ((size_t)12 << 20));     // 1 MB  [256][2048]
    __bf16* ctx = (__bf16*)(ws + ((size_t)13 << 20));     // 32 MB [2][4096][8][256]

    k0a<<<512, 256, 0, stream>>>(x, xT);
    k0b<<<128, 256, 0, stream>>>(VO, vot);
    proj_kernel<<<2048, 256, 0, stream>>>(x, Qw, Kw, qb, kb);
    attn_kernel<<<1024, 256, 0, stream>>>(qb, kb, xT, ctx);
    gemm_out<<<512, 256, 0, stream>>>(ctx, vot, out);
}